// Round 9
// baseline (95.013 us; speedup 1.0000x reference)
//
#include <hip/hip_runtime.h>

// ColorHistogramLoss: soft histogram (Gaussian kernel, 64 bins) over
// pred/target (4,3,256,256) fp32, normalized, cumsum, mean |cdf diff|.
//
// v9: single dispatch. 768 producer blocks (v6 hist verbatim: row-major
//   lane-private LDS, bank = lane%32 data-independent conflict-free,
//   R=4/9-tap ratio recurrence, batched RMW) + 1 waiter block that polls
//   init-free per-block magic flags (poisoned-d_ws-safe), acquire-fences,
//   and does the cdf reduction. Producers never wait (v7 post-mortem:
//   grid-wide sync ~80us/sync on 8 XCDs; here only 1 block spins).
//   v8 post-mortem: occupancy was NOT the constraint (4 blk/CU regressed);
//   ledger across rounds shows per-dispatch overhead ~4-6us dominates the
//   residual over the 41us harness fill -> remove the 2nd dispatch.
//
// Protocol: producer: partial stores -> __syncthreads -> __threadfence
//   (agent release: L2 writeback) -> atomicExch(flag[blk], magic) -> exit.
//   Waiter: agent-scope poll all 768 flags -> __threadfence (acquire:
//   L2 inv) -> plain loads of partials -> scan/cdf/|diff| -> out[0].
//   Deadlock-free: producers independent; waiter is 1/1024 resident slots.

#define BINS 64
#define NCH 12            // B*C = 4*3
#define HW 65536          // 256*256
#define BPC 32            // pixel-chunks (blocks) per channel-image
#define PIX_PER_BLOCK (HW / BPC)              // 2048
#define THREADS 128
#define PPT (PIX_PER_BLOCK / THREADS)         // 16 pixels per thread
#define R 4               // Gaussian support radius (edge weight e^-8)
#define WIN (2 * R + 1)   // 9 taps
#define PADBINS (BINS + 2 * R)   // 72 rows: row = bin + R
#define NW (THREADS / 64) // 2 waves
#define NPROD (2 * NCH * BPC)    // 768 producer blocks
#define FLAG_BASE (NPROD * BINS) // float-index of flag words in d_ws

__device__ __forceinline__ float fast_exp2(float x) {
#if __has_builtin(__builtin_amdgcn_exp2f)
    return __builtin_amdgcn_exp2f(x);   // v_exp_f32
#else
    return exp2f(x);
#endif
}

__device__ __forceinline__ unsigned flag_magic(int blk) {
    // per-block expected value; a uniform fill pattern cannot equal this
    // for any blk except with ~2^-23 probability (and would absmax-fail,
    // not hang, since producers still write real partials).
    return 0x5A17C0DEu ^ ((unsigned)blk * 0x9E3779B9u);
}

// weight for bin i-R+t (t=0..8): exp(-(f-(t-R))^2/2) = CK[t] * P_t,
//   P_0 = exp(-f^2/2 - R*f)  (one exp2)    B = exp(f)  (one exp2)
//   P_{t+1} = P_t * B ;  CK[t] = exp(-(t-R)^2/2)  (compile-time)
__global__ __launch_bounds__(THREADS) void fused_kernel(
        const float* __restrict__ pred,
        const float* __restrict__ target,
        float* __restrict__ ws,
        float* __restrict__ out) {
    constexpr float CK[WIN] = {
        3.3546262790251185e-04f, 1.1108996538242306e-02f,
        1.3533528323661270e-01f, 6.0653065971263342e-01f, 1.0f,
        6.0653065971263342e-01f, 1.3533528323661270e-01f,
        1.1108996538242306e-02f, 3.3546262790251185e-04f };

    unsigned* flags = (unsigned*)(ws + FLAG_BASE);

    __shared__ float h[NW][PADBINS][64];   // 36864 B (producers only)
    __shared__ float part[NW][BINS];
    __shared__ float warr[NCH];

    const int wv   = threadIdx.x >> 6;
    const int lane = threadIdx.x & 63;

    if (blockIdx.x < NPROD) {
        // ---------------- producer: per-block histogram partial ----------
        const int blk   = blockIdx.x;
        const int ch    = blk / BPC;        // 0..23 (0..11 pred, 12..23 tgt)
        const int chunk = blk % BPC;
        const float* src = (ch < NCH) ? (pred + (size_t)ch * HW)
                                      : (target + (size_t)(ch - NCH) * HW);

        // issue global loads first; HBM latency hides under LDS zero
        const float4* src4 = (const float4*)(src + chunk * PIX_PER_BLOCK);
        float4 a = src4[threadIdx.x];
        float4 b = src4[threadIdx.x + THREADS];
        float4 c = src4[threadIdx.x + 2 * THREADS];
        float4 d = src4[threadIdx.x + 3 * THREADS];

        {   // zero h: 2304 float4 / 128 thr = 18 each (exact)
            float4* hz = (float4*)&h[0][0][0];
            #pragma unroll
            for (int t = 0; t < NW * PADBINS * 64 / 4 / THREADS; ++t)
                hz[threadIdx.x + t * THREADS] = make_float4(0.f, 0.f, 0.f, 0.f);
        }
        __syncthreads();

        float px[PPT] = {a.x, a.y, a.z, a.w, b.x, b.y, b.z, b.w,
                         c.x, c.y, c.z, c.w, d.x, d.y, d.z, d.w};

        const float L  = 1.4426950408889634f;    // log2(e)
        const float L2 = 0.7213475204444817f;    // log2(e)/2

        #pragma unroll
        for (int p = 0; p < PPT; ++p) {
            float xt = px[p] * 64.0f - 0.5f;       // bin-center units
            float fi = rintf(xt);
            fi = fminf(fmaxf(fi, 0.0f), 63.0f);    // defensive clamp
            float f  = xt - fi;                    // [-0.5, 0.5]
            int   i  = (int)fi;                    // nearest bin -> rows i..i+8
            float P  = fast_exp2(-L2 * f * f - (float)R * L * f);
            float B  = fast_exp2(L * f);

            // batched RMW: 9 reads (one vaddr, offset:t*256) -> fma -> writes
            float v[WIN];
            #pragma unroll
            for (int t = 0; t < WIN; ++t) v[t] = h[wv][i + t][lane];
            #pragma unroll
            for (int t = 0; t < WIN; ++t) { v[t] = fmaf(P, CK[t], v[t]); P *= B; }
            #pragma unroll
            for (int t = 0; t < WIN; ++t) h[wv][i + t][lane] = v[t];
        }

        __syncthreads();

        // per-wave column reduce: lane j sums 64 columns at row j+R;
        // bank = (j+cc)%32: 2-way alias, free.
        {
            const int j = lane;
            float s = 0.0f;
            #pragma unroll
            for (int cc = 0; cc < 64; ++cc)
                s += h[wv][R + j][(j + cc) & 63];
            part[wv][j] = s;
        }
        __syncthreads();
        if (threadIdx.x < BINS) {
            const int j = threadIdx.x;
            ws[blk * BINS + j] = part[0][j] + part[1][j];
        }

        // publish: block-order stores, agent-release fence, magic flag
        __syncthreads();
        __threadfence();                       // L2 writeback (agent release)
        if (threadIdx.x == 0)
            atomicExch(&flags[blk], flag_magic(blk));   // coherent point
        return;
    }

    // ---------------- waiter: poll flags, then final reduction -----------
    {
        // each thread owns 6 flags: 128*6 = 768
        const int base = threadIdx.x * 6;
        bool all;
        do {
            bool mine = true;
            #pragma unroll
            for (int k = 0; k < 6; ++k) {
                unsigned v = __hip_atomic_load(&flags[base + k],
                                               __ATOMIC_RELAXED,
                                               __HIP_MEMORY_SCOPE_AGENT);
                mine &= (v == flag_magic(base + k));
            }
            all = __syncthreads_and((int)mine) != 0;
            if (!all) __builtin_amdgcn_s_sleep(8);
        } while (!all);
        __threadfence();                       // L2 invalidate (agent acquire)

        // 2 waves x 6 channels each; lane = bin.
        #pragma unroll
        for (int cidx = 0; cidx < 6; ++cidx) {
            const int w = wv * 6 + cidx;
            float ph = 0.0f, th = 0.0f;
            #pragma unroll 8
            for (int c = 0; c < BPC; ++c) {
                ph += ws[(w * BPC + c) * BINS + lane];
                th += ws[((NCH + w) * BPC + c) * BINS + lane];
            }
            // inclusive scan over bins (wave64 shfl_up)
            float ps = ph, ts = th;
            #pragma unroll
            for (int d = 1; d < 64; d <<= 1) {
                float sa = __shfl_up(ps, d, 64);
                float sb = __shfl_up(ts, d, 64);
                if (lane >= d) { ps += sa; ts += sb; }
            }
            float ptot = __shfl(ps, 63, 64);
            float ttot = __shfl(ts, 63, 64);
            float pc = ps / (ptot + 1e-8f);
            float tc = ts / (ttot + 1e-8f);
            float dv = fabsf(pc - tc);
            #pragma unroll
            for (int k = 32; k >= 1; k >>= 1) dv += __shfl_xor(dv, k, 64);
            if (lane == 0) warr[w] = dv;
        }
        __syncthreads();
        if (threadIdx.x == 0) {
            float s = 0.0f;
            #pragma unroll
            for (int i = 0; i < NCH; ++i) s += warr[i];   // same order as v6
            out[0] = s / (float)(NCH * BINS);
        }
    }
}

extern "C" void kernel_launch(void* const* d_in, const int* in_sizes, int n_in,
                              void* d_out, int out_size, void* d_ws, size_t ws_size,
                              hipStream_t stream) {
    const float* pred   = (const float*)d_in[0];
    const float* target = (const float*)d_in[1];
    float* ws  = (float*)d_ws;   // 768*64 partials + 768 flag words
    float* out = (float*)d_out;

    fused_kernel<<<dim3(NPROD + 1), dim3(THREADS), 0, stream>>>(
        pred, target, ws, out);
}

// Round 10
// 76.850 us; speedup vs baseline: 1.2363x; 1.2363x over previous
//
#include <hip/hip_runtime.h>

// ColorHistogramLoss: soft histogram (Gaussian kernel, 64 bins) over
// pred/target (4,3,256,256) fp32, normalized, cumsum, mean |cdf diff|.
//
// v10: single dispatch, coherence-safe producer/consumer.
//   v9 post-mortem: 768x __threadfence (buffer_wbl2 storm) + waiter
//   polling via agent-relaxed LOADS served from its own stale XCD-L2
//   cost ~55us. Rule: cross-XCD protocols must use write-THROUGH stores
//   (atomic store -> IC, no cache maintenance) and poll with RMWs
//   (always executed at the coherence point).
//   Producers (768, v6 hist verbatim): partials via __hip_atomic_store
//   (RELAXED, AGENT) -> __syncthreads (vmcnt drain) -> thread0 RELEASE
//   atomicExch of per-block magic flag (poison-proof). Never wait.
//   Waiter (block 768): polls flags with atomicOr(flag,0) RMW ->
//   ONE __threadfence (single L2 inv) -> plain coalesced partial reads
//   -> scan/cdf/|diff| -> out[0].

#define BINS 64
#define NCH 12            // B*C = 4*3
#define HW 65536          // 256*256
#define BPC 32            // pixel-chunks (blocks) per channel-image
#define PIX_PER_BLOCK (HW / BPC)              // 2048
#define THREADS 128
#define PPT (PIX_PER_BLOCK / THREADS)         // 16 pixels per thread
#define R 4               // Gaussian support radius (edge weight e^-8)
#define WIN (2 * R + 1)   // 9 taps
#define PADBINS (BINS + 2 * R)   // 72 rows: row = bin + R
#define NW (THREADS / 64) // 2 waves
#define NPROD (2 * NCH * BPC)    // 768 producer blocks
#define FLAG_BASE (NPROD * BINS) // float-index of flag words in d_ws

__device__ __forceinline__ float fast_exp2(float x) {
#if __has_builtin(__builtin_amdgcn_exp2f)
    return __builtin_amdgcn_exp2f(x);   // v_exp_f32
#else
    return exp2f(x);
#endif
}

__device__ __forceinline__ unsigned flag_magic(int blk) {
    // per-block expected value; uniform poison cannot match (p ~ 2^-23,
    // and a match would absmax-fail, not hang).
    return 0x5A17C0DEu ^ ((unsigned)blk * 0x9E3779B9u);
}

// weight for bin i-R+t (t=0..8): exp(-(f-(t-R))^2/2) = CK[t] * P_t,
//   P_0 = exp(-f^2/2 - R*f)  (one exp2)    B = exp(f)  (one exp2)
//   P_{t+1} = P_t * B ;  CK[t] = exp(-(t-R)^2/2)  (compile-time)
__global__ __launch_bounds__(THREADS) void fused_kernel(
        const float* __restrict__ pred,
        const float* __restrict__ target,
        float* __restrict__ ws,
        float* __restrict__ out) {
    constexpr float CK[WIN] = {
        3.3546262790251185e-04f, 1.1108996538242306e-02f,
        1.3533528323661270e-01f, 6.0653065971263342e-01f, 1.0f,
        6.0653065971263342e-01f, 1.3533528323661270e-01f,
        1.1108996538242306e-02f, 3.3546262790251185e-04f };

    unsigned* flags = (unsigned*)(ws + FLAG_BASE);

    __shared__ float h[NW][PADBINS][64];   // 36864 B (producers only)
    __shared__ float part[NW][BINS];
    __shared__ float warr[NCH];

    const int wv   = threadIdx.x >> 6;
    const int lane = threadIdx.x & 63;

    if (blockIdx.x < NPROD) {
        // ---------------- producer: per-block histogram partial ----------
        const int blk   = blockIdx.x;
        const int ch    = blk / BPC;        // 0..23 (0..11 pred, 12..23 tgt)
        const int chunk = blk % BPC;
        const float* src = (ch < NCH) ? (pred + (size_t)ch * HW)
                                      : (target + (size_t)(ch - NCH) * HW);

        // issue global loads first; HBM latency hides under LDS zero
        const float4* src4 = (const float4*)(src + chunk * PIX_PER_BLOCK);
        float4 a = src4[threadIdx.x];
        float4 b = src4[threadIdx.x + THREADS];
        float4 c = src4[threadIdx.x + 2 * THREADS];
        float4 d = src4[threadIdx.x + 3 * THREADS];

        {   // zero h: 2304 float4 / 128 thr = 18 each (exact)
            float4* hz = (float4*)&h[0][0][0];
            #pragma unroll
            for (int t = 0; t < NW * PADBINS * 64 / 4 / THREADS; ++t)
                hz[threadIdx.x + t * THREADS] = make_float4(0.f, 0.f, 0.f, 0.f);
        }
        __syncthreads();

        float px[PPT] = {a.x, a.y, a.z, a.w, b.x, b.y, b.z, b.w,
                         c.x, c.y, c.z, c.w, d.x, d.y, d.z, d.w};

        const float L  = 1.4426950408889634f;    // log2(e)
        const float L2 = 0.7213475204444817f;    // log2(e)/2

        #pragma unroll
        for (int p = 0; p < PPT; ++p) {
            float xt = px[p] * 64.0f - 0.5f;       // bin-center units
            float fi = rintf(xt);
            fi = fminf(fmaxf(fi, 0.0f), 63.0f);    // defensive clamp
            float f  = xt - fi;                    // [-0.5, 0.5]
            int   i  = (int)fi;                    // nearest bin -> rows i..i+8
            float P  = fast_exp2(-L2 * f * f - (float)R * L * f);
            float B  = fast_exp2(L * f);

            // batched RMW: 9 reads (one vaddr, offset:t*256) -> fma -> writes
            float v[WIN];
            #pragma unroll
            for (int t = 0; t < WIN; ++t) v[t] = h[wv][i + t][lane];
            #pragma unroll
            for (int t = 0; t < WIN; ++t) { v[t] = fmaf(P, CK[t], v[t]); P *= B; }
            #pragma unroll
            for (int t = 0; t < WIN; ++t) h[wv][i + t][lane] = v[t];
        }

        __syncthreads();

        // per-wave column reduce: lane j sums 64 columns at row j+R;
        // bank = (j+cc)%32: 2-way alias, free.
        {
            const int j = lane;
            float s = 0.0f;
            #pragma unroll
            for (int cc = 0; cc < 64; ++cc)
                s += h[wv][R + j][(j + cc) & 63];
            part[wv][j] = s;
        }
        __syncthreads();

        // write-THROUGH partial stores: land at the coherence point (IC),
        // no L2 writeback instruction anywhere on the producer path.
        if (threadIdx.x < BINS) {
            const int j = threadIdx.x;
            __hip_atomic_store(&ws[blk * BINS + j], part[0][j] + part[1][j],
                               __ATOMIC_RELAXED, __HIP_MEMORY_SCOPE_AGENT);
        }
        __syncthreads();                     // drains vmcnt for all threads
        if (threadIdx.x == 0)
            __hip_atomic_exchange(&flags[blk], flag_magic(blk),
                                  __ATOMIC_RELEASE, __HIP_MEMORY_SCOPE_AGENT);
        return;
    }

    // ---------------- waiter: RMW-poll flags, then final reduction --------
    {
        // each thread owns 6 flags: 128*6 = 768. Poll with atomicOr RMW —
        // RMWs always execute at the coherence point (stale-L2-proof).
        const int base = threadIdx.x * 6;
        for (;;) {
            bool mine = true;
            #pragma unroll
            for (int k = 0; k < 6; ++k) {
                unsigned v = atomicOr(&flags[base + k], 0u);
                mine &= (v == flag_magic(base + k));
            }
            if (__syncthreads_and((int)mine)) break;
            __builtin_amdgcn_s_sleep(16);
        }
        __threadfence();   // ONE acquire fence (single L2 inv) for the reads

        // 2 waves x 6 channels each; lane = bin.
        #pragma unroll
        for (int cidx = 0; cidx < 6; ++cidx) {
            const int w = wv * 6 + cidx;
            float ph = 0.0f, th = 0.0f;
            #pragma unroll 8
            for (int c = 0; c < BPC; ++c) {
                ph += ws[(w * BPC + c) * BINS + lane];
                th += ws[((NCH + w) * BPC + c) * BINS + lane];
            }
            // inclusive scan over bins (wave64 shfl_up)
            float ps = ph, ts = th;
            #pragma unroll
            for (int d = 1; d < 64; d <<= 1) {
                float sa = __shfl_up(ps, d, 64);
                float sb = __shfl_up(ts, d, 64);
                if (lane >= d) { ps += sa; ts += sb; }
            }
            float ptot = __shfl(ps, 63, 64);
            float ttot = __shfl(ts, 63, 64);
            float pc = ps / (ptot + 1e-8f);
            float tc = ts / (ttot + 1e-8f);
            float dv = fabsf(pc - tc);
            #pragma unroll
            for (int k = 32; k >= 1; k >>= 1) dv += __shfl_xor(dv, k, 64);
            if (lane == 0) warr[w] = dv;
        }
        __syncthreads();
        if (threadIdx.x == 0) {
            float s = 0.0f;
            #pragma unroll
            for (int i = 0; i < NCH; ++i) s += warr[i];   // same order as v6
            out[0] = s / (float)(NCH * BINS);
        }
    }
}

extern "C" void kernel_launch(void* const* d_in, const int* in_sizes, int n_in,
                              void* d_out, int out_size, void* d_ws, size_t ws_size,
                              hipStream_t stream) {
    const float* pred   = (const float*)d_in[0];
    const float* target = (const float*)d_in[1];
    float* ws  = (float*)d_ws;   // 768*64 partials + 768 flag words
    float* out = (float*)d_out;

    fused_kernel<<<dim3(NPROD + 1), dim3(THREADS), 0, stream>>>(
        pred, target, ws, out);
}

// Round 11
// 64.364 us; speedup vs baseline: 1.4762x; 1.1940x over previous
//
#include <hip/hip_runtime.h>

// ColorHistogramLoss: soft histogram (Gaussian kernel, 64 bins) over
// pred/target (4,3,256,256) fp32, normalized, cumsum, mean |cdf diff|.
//
// v11 == v6 (empirical optimum, 64.8us): REVERT after fusion attempts.
//   Session ledger:
//   - LDS atomicAdd path ~200cy/op regardless of contention (v2/v3=137us)
//     -> plain ds RMW on lane-private columns (v4: 65.4).
//   - Row-major h[wave][bin][lane]: bank = lane%32, DATA-INDEPENDENT
//     conflict-free. Transposed/b64 merging (v5) has data-dependent bank
//     clumping: regressed. R=4 9-tap window (v6: 64.8, absmax 0.0).
//   - Op-count slope flat (~0.075us per op/px): scatter is at its
//     latency/issue knee, not issue-bound.
//   - Occupancy 4 blk/CU (v8): regressed (generation tail).
//   - Fusion: grid.sync (v7: +130us), fence-storm waiter (v9: +30),
//     coherent RMW-poll waiter (v10: +12) — all lose to two dispatches.
//   Floor: harness d_ws poison fill 41us (82% HBM peak) + hist ~11
//   + final ~3 + dispatch gaps ~8.
//
// Structure:
//   hist_kernel : 768 blocks x 128 thr (3 blocks/CU); h[2][72][64]
//                 row-major lane-private, batched read->fma->write RMW,
//                 staggered column reduce, partial store to d_ws
//   final_kernel: 1 block x 768 thr (12 waves); sum 32 chunk partials
//                 (coalesced), wave scan -> cdf -> |diff| -> mean

#define BINS 64
#define NCH 12            // B*C = 4*3
#define HW 65536          // 256*256
#define BPC 32            // pixel-chunks (blocks) per channel-image
#define PIX_PER_BLOCK (HW / BPC)              // 2048
#define THREADS 128
#define PPT (PIX_PER_BLOCK / THREADS)         // 16 pixels per thread
#define R 4               // Gaussian support radius (edge weight e^-8)
#define WIN (2 * R + 1)   // 9 taps
#define PADBINS (BINS + 2 * R)   // 72 rows: row = bin + R, bins -4..67
#define NW (THREADS / 64) // 2 waves

__device__ __forceinline__ float fast_exp2(float x) {
#if __has_builtin(__builtin_amdgcn_exp2f)
    return __builtin_amdgcn_exp2f(x);   // v_exp_f32
#else
    return exp2f(x);
#endif
}

// weight for bin i-R+t (t=0..8): exp(-(f-(t-R))^2/2) = CK[t] * P_t,
//   P_0 = exp(-f^2/2 - R*f)  (one exp2)    B = exp(f)  (one exp2)
//   P_{t+1} = P_t * B ;  CK[t] = exp(-(t-R)^2/2)  (compile-time)
// P_t = exp(-f^2/2 + (t-R)f) in [e^-2.125, e^2] — tiny fp32 range.
__global__ __launch_bounds__(THREADS) void hist_kernel(
        const float* __restrict__ pred,
        const float* __restrict__ target,
        float* __restrict__ part_out) {
    constexpr float CK[WIN] = {
        3.3546262790251185e-04f, 1.1108996538242306e-02f,
        1.3533528323661270e-01f, 6.0653065971263342e-01f, 1.0f,
        6.0653065971263342e-01f, 1.3533528323661270e-01f,
        1.1108996538242306e-02f, 3.3546262790251185e-04f };

    const int blk   = blockIdx.x;
    const int ch    = blk / BPC;        // 0..23 (0..11 pred, 12..23 target)
    const int chunk = blk % BPC;
    const float* src = (ch < NCH) ? (pred + (size_t)ch * HW)
                                  : (target + (size_t)(ch - NCH) * HW);

    // row-major lane-private columns: bank = lane%32 for every tap row,
    // conflict-free (2-way) independent of pixel data. No atomics.
    __shared__ float h[NW][PADBINS][64];   // 36864 B
    __shared__ float part[NW][BINS];

    const int wv   = threadIdx.x >> 6;
    const int lane = threadIdx.x & 63;

    // zero h: 9216 dwords = 2304 float4 / 128 thr = 18 each (exact)
    {
        float4* hz = (float4*)&h[0][0][0];
        #pragma unroll
        for (int t = 0; t < NW * PADBINS * 64 / 4 / THREADS; ++t)
            hz[threadIdx.x + t * THREADS] = make_float4(0.f, 0.f, 0.f, 0.f);
    }
    __syncthreads();

    // 512 float4 per block; thread t loads f4[t + k*128], k=0..3 (coalesced).
    const float4* src4 = (const float4*)(src + chunk * PIX_PER_BLOCK);
    float4 a = src4[threadIdx.x];
    float4 b = src4[threadIdx.x + THREADS];
    float4 c = src4[threadIdx.x + 2 * THREADS];
    float4 d = src4[threadIdx.x + 3 * THREADS];
    float px[PPT] = {a.x, a.y, a.z, a.w, b.x, b.y, b.z, b.w,
                     c.x, c.y, c.z, c.w, d.x, d.y, d.z, d.w};

    const float L  = 1.4426950408889634f;    // log2(e)
    const float L2 = 0.7213475204444817f;    // log2(e)/2

    #pragma unroll
    for (int p = 0; p < PPT; ++p) {
        float xt = px[p] * 64.0f - 0.5f;       // bin-center units
        float fi = rintf(xt);
        fi = fminf(fmaxf(fi, 0.0f), 63.0f);    // defensive clamp
        float f  = xt - fi;                    // [-0.5, 0.5]
        int   i  = (int)fi;                    // nearest bin -> rows i..i+8
        float P  = fast_exp2(-L2 * f * f - (float)R * L * f);
        float B  = fast_exp2(L * f);

        // batched RMW: 9 reads (one vaddr, offset:t*256) -> 9 fma -> 9 writes
        float v[WIN];
        #pragma unroll
        for (int t = 0; t < WIN; ++t) v[t] = h[wv][i + t][lane];
        #pragma unroll
        for (int t = 0; t < WIN; ++t) { v[t] = fmaf(P, CK[t], v[t]); P *= B; }
        #pragma unroll
        for (int t = 0; t < WIN; ++t) h[wv][i + t][lane] = v[t];
    }

    __syncthreads();

    // Per-wave column reduce: lane j sums 64 lane-columns at row j+R.
    // bank = ((j+R)*64 + j+cc) % 32 = (j+cc)%32: 2-way alias, free.
    {
        const int j = lane;
        float s = 0.0f;
        #pragma unroll
        for (int cc = 0; cc < 64; ++cc)
            s += h[wv][R + j][(j + cc) & 63];
        part[wv][j] = s;
    }
    __syncthreads();
    if (threadIdx.x < BINS) {
        const int j = threadIdx.x;
        part_out[blk * BINS + j] = part[0][j] + part[1][j];  // plain store
    }
}

__global__ __launch_bounds__(NCH * 64) void final_kernel(
        const float* __restrict__ part, float* __restrict__ out) {
    const int w    = threadIdx.x >> 6;   // 0..11 -> (b,c) channel
    const int lane = threadIdx.x & 63;   // bin

    // sum the 32 chunk-partials for pred and target (coalesced per c).
    float ph = 0.0f, th = 0.0f;
    #pragma unroll 8
    for (int c = 0; c < BPC; ++c) {
        ph += part[(w * BPC + c) * BINS + lane];
        th += part[((NCH + w) * BPC + c) * BINS + lane];
    }

    // inclusive scan over bins (wave64 shfl_up)
    float ps = ph, ts = th;
    #pragma unroll
    for (int d = 1; d < 64; d <<= 1) {
        float a = __shfl_up(ps, d, 64);
        float b = __shfl_up(ts, d, 64);
        if (lane >= d) { ps += a; ts += b; }
    }
    float ptot = __shfl(ps, 63, 64);
    float ttot = __shfl(ts, 63, 64);
    float pc = ps / (ptot + 1e-8f);
    float tc = ts / (ttot + 1e-8f);
    float dv = fabsf(pc - tc);

    // wave reduce
    #pragma unroll
    for (int k = 32; k >= 1; k >>= 1) dv += __shfl_xor(dv, k, 64);

    __shared__ float warr[NCH];
    if (lane == 0) warr[w] = dv;
    __syncthreads();
    if (threadIdx.x == 0) {
        float s = 0.0f;
        #pragma unroll
        for (int i = 0; i < NCH; ++i) s += warr[i];
        out[0] = s / (float)(NCH * BINS);
    }
}

extern "C" void kernel_launch(void* const* d_in, const int* in_sizes, int n_in,
                              void* d_out, int out_size, void* d_ws, size_t ws_size,
                              hipStream_t stream) {
    const float* pred   = (const float*)d_in[0];
    const float* target = (const float*)d_in[1];
    float* part = (float*)d_ws;          // 768*64 floats = 196 KB partials
    float* out  = (float*)d_out;

    hist_kernel<<<dim3(2 * NCH * BPC), dim3(THREADS), 0, stream>>>(
        pred, target, part);
    final_kernel<<<dim3(1), dim3(NCH * 64), 0, stream>>>(part, out);
}